// Round 2
// baseline (1521.869 us; speedup 1.0000x reference)
//
#include <hip/hip_runtime.h>
#include <hip/hip_bf16.h>
#include <stdint.h>

typedef __attribute__((ext_vector_type(8))) short short8;
typedef __attribute__((ext_vector_type(4))) float f32x4;

__device__ __forceinline__ float b2f(ushort u) {
  union { uint32_t i; float f; } v; v.i = ((uint32_t)u) << 16; return v.f;
}
__device__ __forceinline__ ushort f2b(float f) {
  union { float f; uint32_t i; } v; v.f = f;
  uint32_t x = v.i;
  uint32_t r = x + 0x7FFFu + ((x >> 16) & 1u);
  return (ushort)(r >> 16);
}
__device__ __forceinline__ uint pk2(float lo, float hi) {
  return (uint)f2b(lo) | ((uint)f2b(hi) << 16);
}
__device__ __forceinline__ float lo2f(uint v) { return b2f((ushort)(v & 0xFFFFu)); }
__device__ __forceinline__ float hi2f(uint v) { return b2f((ushort)(v >> 16)); }

__device__ __forceinline__ uint4 pkf8(float4 a, float4 b) {
  uint4 o;
  o.x = pk2(a.x, a.y); o.y = pk2(a.z, a.w);
  o.z = pk2(b.x, b.y); o.w = pk2(b.z, b.w);
  return o;
}
__device__ __forceinline__ uint sub2(uint a, uint b) {
  return pk2(lo2f(a) - lo2f(b), hi2f(a) - hi2f(b));
}
__device__ __forceinline__ uint4 sub8(uint4 a, uint4 b) {
  uint4 o; o.x = sub2(a.x,b.x); o.y = sub2(a.y,b.y); o.z = sub2(a.z,b.z); o.w = sub2(a.w,b.w); return o;
}
__device__ __forceinline__ uint relu2(uint v) {
  uint lo = (v & 0x8000u) ? 0u : (v & 0xFFFFu);
  uint hi = (v & 0x80000000u) ? 0u : (v & 0xFFFF0000u);
  return lo | hi;
}
__device__ __forceinline__ uint4 relu8(uint4 v) {
  uint4 o; o.x = relu2(v.x); o.y = relu2(v.y); o.z = relu2(v.z); o.w = relu2(v.w); return o;
}

__global__ void zero_ints(int* __restrict__ p, int n) {
  int i = blockIdx.x * blockDim.x + threadIdx.x;
  if (i < n) p[i] = 0;
}

// ---------- weight prep: transposes + bf16 + fused conv|edge weight + fused bias ----------
__global__ void prep_weights(const float* __restrict__ wn, const float* __restrict__ we,
                             const float* __restrict__ cw, const float* __restrict__ ow,
                             const float* __restrict__ cb, const float* __restrict__ be,
                             ushort* __restrict__ wnT, ushort* __restrict__ weT,
                             ushort* __restrict__ cweT, ushort* __restrict__ owT,
                             float* __restrict__ cbe) {
  int i = blockIdx.x * blockDim.x + threadIdx.x;
  if (i < 16384) {
    int n = i >> 7, k = i & 127; wnT[n*128+k] = f2b(wn[k*128+n]);
  } else if (i < 32768) {
    int j = i - 16384; int n = j >> 7, k = j & 127; owT[n*128+k] = f2b(ow[k*128+n]);
  } else if (i < 53248) {
    int j = i - 32768;           // 128*160 = 20480 entries
    int n = j / 160, k = j % 160;
    cweT[n*160+k] = (k < 128) ? f2b(cw[k*128+n]) : f2b(we[(k-128)*128+n]);
  } else if (i < 57344) {
    int j = i - 53248; int n = j >> 5, k = j & 31; weT[n*32+k] = f2b(we[k*128+n]);
  } else if (i < 57472) {
    int j = i - 57344; cbe[j] = cb[j] + be[j];
  }
}

// ---------- CSR build ----------
__global__ void count_dst(const int* __restrict__ dst, int* __restrict__ counts, int E) {
  for (int i = blockIdx.x * blockDim.x + threadIdx.x; i < E; i += gridDim.x * blockDim.x)
    atomicAdd(&counts[dst[i]], 1);
}
__global__ __launch_bounds__(1024) void scan_offsets(
    const int* __restrict__ counts, int* __restrict__ off,
    int* __restrict__ cursor, int N) {
  __shared__ int part[1024];
  int t = threadIdx.x;
  int chunk = (N + 1023) >> 10;
  int lo = t * chunk, hi = min(lo + chunk, N);
  int s = 0;
  for (int i = lo; i < hi; ++i) s += counts[i];
  part[t] = s;
  __syncthreads();
  for (int d = 1; d < 1024; d <<= 1) {
    int v = (t >= d) ? part[t - d] : 0;
    __syncthreads();
    part[t] += v;
    __syncthreads();
  }
  int run = (t > 0) ? part[t - 1] : 0;
  for (int i = lo; i < hi; ++i) {
    off[i] = run; cursor[i] = run; run += counts[i];
  }
  if (t == 1023) off[N] = part[1023];
}
__global__ void fill_csr(const int* __restrict__ dst, int* __restrict__ cursor,
                         int* __restrict__ eids, int E) {
  for (int i = blockIdx.x * blockDim.x + threadIdx.x; i < E; i += gridDim.x * blockDim.x) {
    int p = atomicAdd(&cursor[dst[i]], 1);
    eids[p] = i;
  }
}

// ---------- inl = bf16(node_feat @ Wn + bn) ----------
__global__ __launch_bounds__(256) void node_linear(
    const float* __restrict__ nf, const ushort* __restrict__ wnT,
    const float* __restrict__ bn, ushort* __restrict__ inl, int N) {
  __shared__ ushort Als[64][136];
  __shared__ ushort Bls[128][136];
  int tid = threadIdx.x;
  int n0 = blockIdx.x * 64;
  { // stage B (Wn^T bf16, 128x128)
    int row = tid >> 1, h = tid & 1;
    const uint4* gp = (const uint4*)(wnT + row*128 + h*64);
    uint4* lp = (uint4*)&Bls[row][h*64];
    #pragma unroll
    for (int i = 0; i < 8; ++i) lp[i] = gp[i];
  }
  { // stage A (node_feat f32 -> bf16)
    int r = tid >> 2, q = tid & 3;
    int n = n0 + r;
    uint4* lp = (uint4*)&Als[r][q*32];
    if (n < N) {
      const float4* fp = (const float4*)(nf + (size_t)n*128 + q*32);
      #pragma unroll
      for (int i = 0; i < 4; ++i) lp[i] = pkf8(fp[2*i], fp[2*i+1]);
    } else {
      uint4 z = {0,0,0,0};
      #pragma unroll
      for (int i = 0; i < 4; ++i) lp[i] = z;
    }
  }
  __syncthreads();
  int l = tid & 63, w = tid >> 6, quad = l >> 4, mr = l & 15;
  f32x4 acc[8];
  #pragma unroll
  for (int nt = 0; nt < 8; ++nt) acc[nt] = (f32x4){0.f,0.f,0.f,0.f};
  #pragma unroll
  for (int kk = 0; kk < 4; ++kk) {
    short8 a = *(const short8*)&Als[w*16 + mr][kk*32 + quad*8];
    #pragma unroll
    for (int nt = 0; nt < 8; ++nt) {
      short8 b = *(const short8*)&Bls[nt*16 + mr][kk*32 + quad*8];
      acc[nt] = __builtin_amdgcn_mfma_f32_16x16x32_bf16(a, b, acc[nt], 0, 0, 0);
    }
  }
  #pragma unroll
  for (int nt = 0; nt < 8; ++nt) {
    int col = nt*16 + mr;
    float bias = bn[col];
    #pragma unroll
    for (int rg = 0; rg < 4; ++rg) {
      int n = n0 + w*16 + quad*4 + rg;
      if (n < N) inl[(size_t)n*128 + col] = f2b(acc[nt][rg] + bias);
    }
  }
}

// ---------- cur = relu(inl[src] + ef @ We + be) ----------
__global__ __launch_bounds__(256) void edge_init(
    const float* __restrict__ ef, const ushort* __restrict__ weT,
    const float* __restrict__ be, const int* __restrict__ esrc,
    const ushort* __restrict__ inl, ushort* __restrict__ cur, int E) {
  __shared__ ushort Als[64][40];
  __shared__ ushort Bls[128][40];
  int tid = threadIdx.x;
  int e0 = blockIdx.x * 64;
  { // stage B (We^T bf16, 128 n x 32 k)
    int row = tid >> 1, h = tid & 1;
    const uint4* gp = (const uint4*)(weT + row*32 + h*16);
    uint4* lp = (uint4*)&Bls[row][h*16];
    lp[0] = gp[0]; lp[1] = gp[1];
  }
  { // stage A (edge_feat f32 64x32 -> bf16)
    int r = tid >> 2, q = tid & 3;
    int e = e0 + r;
    const float4* fp = (const float4*)(ef + (size_t)e*32 + q*8);
    *(uint4*)&Als[r][q*8] = pkf8(fp[0], fp[1]);
  }
  __syncthreads();
  int l = tid & 63, w = tid >> 6, quad = l >> 4, mr = l & 15;
  short8 a = *(const short8*)&Als[w*16 + mr][quad*8];
  f32x4 zero = (f32x4){0.f,0.f,0.f,0.f};
  f32x4 acc[8];
  #pragma unroll
  for (int nt = 0; nt < 8; ++nt) {
    short8 b = *(const short8*)&Bls[nt*16 + mr][quad*8];
    acc[nt] = __builtin_amdgcn_mfma_f32_16x16x32_bf16(a, b, zero, 0, 0, 0);
  }
  int sfour[4];
  #pragma unroll
  for (int rg = 0; rg < 4; ++rg) sfour[rg] = esrc[e0 + w*16 + quad*4 + rg];
  #pragma unroll
  for (int nt = 0; nt < 8; ++nt) {
    int col = nt*16 + mr;
    float bias = be[col];
    #pragma unroll
    for (int rg = 0; rg < 4; ++rg) {
      int e = e0 + w*16 + quad*4 + rg;
      float v = acc[nt][rg] + bias + b2f(inl[(size_t)sfour[rg]*128 + col]);
      cur[(size_t)e*128 + col] = f2b(fmaxf(v, 0.f));
    }
  }
}

// ---------- segment-sum of cur rows into nodes via CSR ----------
__global__ __launch_bounds__(256) void segsum(
    const ushort* __restrict__ cur, const int* __restrict__ off,
    const int* __restrict__ eids, ushort* __restrict__ nagg, int N) {
  int w = threadIdx.x >> 6, l = threadIdx.x & 63;
  int n = blockIdx.x * 4 + w;
  if (n >= N) return;
  int i = off[n], end = off[n + 1];
  float s0 = 0.f, s1 = 0.f;
  for (; i + 2 <= end; i += 2) {
    int ea = eids[i], eb = eids[i + 1];
    uint va = *(const uint*)(cur + (size_t)ea*128 + 2*l);
    uint vb = *(const uint*)(cur + (size_t)eb*128 + 2*l);
    s0 += lo2f(va) + lo2f(vb);
    s1 += hi2f(va) + hi2f(vb);
  }
  if (i < end) {
    int ea = eids[i];
    uint va = *(const uint*)(cur + (size_t)ea*128 + 2*l);
    s0 += lo2f(va); s1 += hi2f(va);
  }
  *(uint*)(nagg + (size_t)n*128 + 2*l) = pk2(s0, s1);
}

// ---------- cur = relu([nagg[src]-cur[e^1] | ef] @ [Wc|We]^T + (cb+be) + inl[src]) ----------
// K = 160: first 128 = conv_W, last 32 = We (recomputes input_message, no im array)
__global__ __launch_bounds__(256) void conv_step(
    ushort* __restrict__ cur, const ushort* __restrict__ nagg,
    const ushort* __restrict__ inl, const float* __restrict__ ef,
    const ushort* __restrict__ cweT, const float* __restrict__ cbe,
    const int* __restrict__ esrc, int E) {
  __shared__ ushort Als[64][168];   // 64 x 160 (pad->168; 21x16B rows)
  __shared__ ushort Bls[128][168];  // 128 x 160
  int tid = threadIdx.x;
  int e0 = blockIdx.x * 64;
  { // stage B ([Wc|We]^T bf16, 128 n x 160 k)
    int row = tid >> 1, h = tid & 1;
    const uint4* gp = (const uint4*)(cweT + row*160 + h*80);
    uint4* lp = (uint4*)&Bls[row][h*80];
    #pragma unroll
    for (int i = 0; i < 10; ++i) lp[i] = gp[i];
  }
  { // stage A: cols[0,128) = nagg[src[e]] - cur[e^1]; cols[128,160) = bf16(ef[e])
    int r = tid >> 2, q = tid & 3;
    int e = e0 + r;
    int s = esrc[e];
    const uint4* cp = (const uint4*)(cur + (size_t)(e ^ 1)*128 + q*32);
    const uint4* np = (const uint4*)(nagg + (size_t)s*128 + q*32);
    uint4* lp = (uint4*)&Als[r][q*32];
    #pragma unroll
    for (int i = 0; i < 4; ++i) lp[i] = sub8(np[i], cp[i]);
    const float4* fp = (const float4*)(ef + (size_t)e*32 + q*8);
    *(uint4*)&Als[r][128 + q*8] = pkf8(fp[0], fp[1]);
  }
  __syncthreads();
  int l = tid & 63, w = tid >> 6, quad = l >> 4, mr = l & 15;
  f32x4 acc[8];
  #pragma unroll
  for (int nt = 0; nt < 8; ++nt) acc[nt] = (f32x4){0.f,0.f,0.f,0.f};
  #pragma unroll
  for (int kk = 0; kk < 5; ++kk) {
    short8 a = *(const short8*)&Als[w*16 + mr][kk*32 + quad*8];
    #pragma unroll
    for (int nt = 0; nt < 8; ++nt) {
      short8 b = *(const short8*)&Bls[nt*16 + mr][kk*32 + quad*8];
      acc[nt] = __builtin_amdgcn_mfma_f32_16x16x32_bf16(a, b, acc[nt], 0, 0, 0);
    }
  }
  // all staging reads of cur happened before the barrier; tile-local in-place write is safe
  int sfour[4];
  #pragma unroll
  for (int rg = 0; rg < 4; ++rg) sfour[rg] = esrc[e0 + w*16 + quad*4 + rg];
  #pragma unroll
  for (int nt = 0; nt < 8; ++nt) {
    int col = nt*16 + mr;
    float bias = cbe[col];
    #pragma unroll
    for (int rg = 0; rg < 4; ++rg) {
      int e = e0 + w*16 + quad*4 + rg;
      float v = acc[nt][rg] + bias + b2f(inl[(size_t)sfour[rg]*128 + col]);
      cur[(size_t)e*128 + col] = f2b(fmaxf(v, 0.f));
    }
  }
}

// ---------- ract(bf16) = relu(relu(nagg) @ Wo + ob) ----------
__global__ __launch_bounds__(256) void out_linear(
    const ushort* __restrict__ nagg, const ushort* __restrict__ owT,
    const float* __restrict__ ob, ushort* __restrict__ ract, int N) {
  __shared__ ushort Als[64][136];
  __shared__ ushort Bls[128][136];
  int tid = threadIdx.x;
  int n0 = blockIdx.x * 64;
  {
    int row = tid >> 1, h = tid & 1;
    const uint4* gp = (const uint4*)(owT + row*128 + h*64);
    uint4* lp = (uint4*)&Bls[row][h*64];
    #pragma unroll
    for (int i = 0; i < 8; ++i) lp[i] = gp[i];
  }
  {
    int r = tid >> 2, q = tid & 3;
    int n = n0 + r;
    uint4* lp = (uint4*)&Als[r][q*32];
    if (n < N) {
      const uint4* gp = (const uint4*)(nagg + (size_t)n*128 + q*32);
      #pragma unroll
      for (int i = 0; i < 4; ++i) lp[i] = relu8(gp[i]);
    } else {
      uint4 z = {0,0,0,0};
      #pragma unroll
      for (int i = 0; i < 4; ++i) lp[i] = z;
    }
  }
  __syncthreads();
  int l = tid & 63, w = tid >> 6, quad = l >> 4, mr = l & 15;
  f32x4 acc[8];
  #pragma unroll
  for (int nt = 0; nt < 8; ++nt) acc[nt] = (f32x4){0.f,0.f,0.f,0.f};
  #pragma unroll
  for (int kk = 0; kk < 4; ++kk) {
    short8 a = *(const short8*)&Als[w*16 + mr][kk*32 + quad*8];
    #pragma unroll
    for (int nt = 0; nt < 8; ++nt) {
      short8 b = *(const short8*)&Bls[nt*16 + mr][kk*32 + quad*8];
      acc[nt] = __builtin_amdgcn_mfma_f32_16x16x32_bf16(a, b, acc[nt], 0, 0, 0);
    }
  }
  #pragma unroll
  for (int nt = 0; nt < 8; ++nt) {
    int col = nt*16 + mr;
    float bias = ob[col];
    #pragma unroll
    for (int rg = 0; rg < 4; ++rg) {
      int n = n0 + w*16 + quad*4 + rg;
      if (n < N) ract[(size_t)n*128 + col] = f2b(fmaxf(acc[nt][rg] + bias, 0.f));
    }
  }
}

// ---------- per-graph node ranges (graph_ids is sorted) ----------
__global__ void graph_offsets(const int* __restrict__ gids, int* __restrict__ goff,
                              int N, int G) {
  for (int i = threadIdx.x; i <= N; i += blockDim.x) {
    int pg = (i == 0) ? -1 : gids[i - 1];
    int cg = (i == N) ? G : gids[i];
    for (int g = pg + 1; g <= cg; ++g) goff[g] = i;
  }
}

// ---------- pool nodes per graph (bf16 in, f32 out) ----------
__global__ __launch_bounds__(256) void graph_pool(
    const ushort* __restrict__ ract, const int* __restrict__ goff,
    float* __restrict__ out, int G) {
  __shared__ float red0[256];
  __shared__ float red1[256];
  int g = blockIdx.x;
  int t = threadIdx.x;
  int c2 = t & 63, rp = t >> 6;      // 2 cols per lane, 4 row-partitions
  int beg = goff[g], end = goff[g + 1];
  float s0 = 0.f, s1 = 0.f;
  for (int n = beg + rp; n < end; n += 4) {
    uint v = *(const uint*)(ract + (size_t)n*128 + 2*c2);
    s0 += lo2f(v); s1 += hi2f(v);
  }
  red0[t] = s0; red1[t] = s1;
  __syncthreads();
  if (rp == 0) {
    float v0 = red0[c2] + red0[c2 + 64] + red0[c2 + 128] + red0[c2 + 192];
    float v1 = red1[c2] + red1[c2 + 64] + red1[c2 + 128] + red1[c2 + 192];
    float2 o; o.x = fmaxf(v0, 0.f); o.y = fmaxf(v1, 0.f);
    *(float2*)(out + (size_t)g*128 + 2*c2) = o;
  }
}

extern "C" void kernel_launch(void* const* d_in, const int* in_sizes, int n_in,
                              void* d_out, int out_size, void* d_ws, size_t ws_size,
                              hipStream_t stream) {
  const float* node_feat = (const float*)d_in[0];
  const float* edge_feat = (const float*)d_in[1];
  const float* wn = (const float*)d_in[2];
  const float* bn = (const float*)d_in[3];
  const float* we = (const float*)d_in[4];
  const float* be = (const float*)d_in[5];
  const float* cw = (const float*)d_in[6];
  const float* cb = (const float*)d_in[7];
  const float* ow = (const float*)d_in[8];
  const float* ob = (const float*)d_in[9];
  const int* esrc = (const int*)d_in[10];
  const int* edst = (const int*)d_in[11];
  const int* gids = (const int*)d_in[12];
  int N = in_sizes[0] / 128;
  int E = in_sizes[10];
  int G = out_size / 128;
  float* out = (float*)d_out;

  char* p = (char*)d_ws;
  auto alloc = [&](size_t bytes) {
    char* r = p;
    p += (bytes + 255) & ~(size_t)255;
    return r;
  };
  // total ws use: ~234 MB (cur 204.8 + inl 12.8 + nagg 12.8 + eids 3.2 + ints ~0.6 + weights ~0.12)
  ushort* cur     = (ushort*)alloc((size_t)E * 128 * 2);
  ushort* inl     = (ushort*)alloc((size_t)N * 128 * 2);   // also reused as ract after last conv
  ushort* nagg    = (ushort*)alloc((size_t)N * 128 * 2);
  int*    eids    = (int*)   alloc((size_t)E * 4);
  int*    counts  = (int*)   alloc((size_t)N * 4);
  int*    off     = (int*)   alloc((size_t)(N + 1) * 4);
  int*    cursor  = (int*)   alloc((size_t)N * 4);
  int*    goff    = (int*)   alloc((size_t)(G + 1) * 4);
  ushort* wnT     = (ushort*)alloc(128 * 128 * 2);
  ushort* weT     = (ushort*)alloc(128 * 32 * 2);
  ushort* cweT    = (ushort*)alloc(128 * 160 * 2);
  ushort* owT     = (ushort*)alloc(128 * 128 * 2);
  float*  cbe     = (float*) alloc(128 * 4);
  ushort* ract    = inl;  // alias: inl dead after last conv_step
  (void)ws_size; (void)n_in;

  zero_ints<<<(N + 255) / 256, 256, 0, stream>>>(counts, N);
  prep_weights<<<225, 256, 0, stream>>>(wn, we, cw, ow, cb, be, wnT, weT, cweT, owT, cbe);
  count_dst<<<1024, 256, 0, stream>>>(edst, counts, E);
  scan_offsets<<<1, 1024, 0, stream>>>(counts, off, cursor, N);
  fill_csr<<<1024, 256, 0, stream>>>(edst, cursor, eids, E);

  node_linear<<<(N + 63) / 64, 256, 0, stream>>>(node_feat, wnT, bn, inl, N);
  edge_init<<<E / 64, 256, 0, stream>>>(edge_feat, weT, be, esrc, inl, cur, E);

  for (int it = 0; it < 3; ++it) {
    segsum<<<(N + 3) / 4, 256, 0, stream>>>(cur, off, eids, nagg, N);
    conv_step<<<E / 64, 256, 0, stream>>>(cur, nagg, inl, edge_feat, cweT, cbe, esrc, E);
  }
  segsum<<<(N + 3) / 4, 256, 0, stream>>>(cur, off, eids, nagg, N);
  out_linear<<<(N + 63) / 64, 256, 0, stream>>>(nagg, owT, ob, ract, N);
  graph_offsets<<<1, 256, 0, stream>>>(gids, goff, N, G);
  graph_pool<<<G, 256, 0, stream>>>(ract, goff, out, G);
}

// Round 3
// 1333.569 us; speedup vs baseline: 1.1412x; 1.1412x over previous
//
#include <hip/hip_runtime.h>
#include <hip/hip_bf16.h>
#include <stdint.h>

typedef __attribute__((ext_vector_type(8))) short short8;
typedef __attribute__((ext_vector_type(4))) float f32x4;

__device__ __forceinline__ float b2f(ushort u) {
  union { uint32_t i; float f; } v; v.i = ((uint32_t)u) << 16; return v.f;
}
__device__ __forceinline__ ushort f2b(float f) {
  union { float f; uint32_t i; } v; v.f = f;
  uint32_t x = v.i;
  uint32_t r = x + 0x7FFFu + ((x >> 16) & 1u);
  return (ushort)(r >> 16);
}
__device__ __forceinline__ uint pk2(float lo, float hi) {
  return (uint)f2b(lo) | ((uint)f2b(hi) << 16);
}
__device__ __forceinline__ float lo2f(uint v) { return b2f((ushort)(v & 0xFFFFu)); }
__device__ __forceinline__ float hi2f(uint v) { return b2f((ushort)(v >> 16)); }

__device__ __forceinline__ uint4 pkf8(float4 a, float4 b) {
  uint4 o;
  o.x = pk2(a.x, a.y); o.y = pk2(a.z, a.w);
  o.z = pk2(b.x, b.y); o.w = pk2(b.z, b.w);
  return o;
}
__device__ __forceinline__ uint sub2(uint a, uint b) {
  return pk2(lo2f(a) - lo2f(b), hi2f(a) - hi2f(b));
}
__device__ __forceinline__ uint4 sub8(uint4 a, uint4 b) {
  uint4 o; o.x = sub2(a.x,b.x); o.y = sub2(a.y,b.y); o.z = sub2(a.z,b.z); o.w = sub2(a.w,b.w); return o;
}
__device__ __forceinline__ uint relu2(uint v) {
  uint lo = (v & 0x8000u) ? 0u : (v & 0xFFFFu);
  uint hi = (v & 0x80000000u) ? 0u : (v & 0xFFFF0000u);
  return lo | hi;
}
__device__ __forceinline__ uint4 relu8(uint4 v) {
  uint4 o; o.x = relu2(v.x); o.y = relu2(v.y); o.z = relu2(v.z); o.w = relu2(v.w); return o;
}

__global__ void zero_ints(int* __restrict__ p, int n) {
  int i = blockIdx.x * blockDim.x + threadIdx.x;
  if (i < n) p[i] = 0;
}

// ---------- weight prep: transposes + bf16 + fused conv|edge weight + fused bias ----------
__global__ void prep_weights(const float* __restrict__ wn, const float* __restrict__ we,
                             const float* __restrict__ cw, const float* __restrict__ ow,
                             const float* __restrict__ cb, const float* __restrict__ be,
                             ushort* __restrict__ wnT, ushort* __restrict__ weT,
                             ushort* __restrict__ cweT, ushort* __restrict__ owT,
                             float* __restrict__ cbe) {
  int i = blockIdx.x * blockDim.x + threadIdx.x;
  if (i < 16384) {
    int n = i >> 7, k = i & 127; wnT[n*128+k] = f2b(wn[k*128+n]);
  } else if (i < 32768) {
    int j = i - 16384; int n = j >> 7, k = j & 127; owT[n*128+k] = f2b(ow[k*128+n]);
  } else if (i < 53248) {
    int j = i - 32768;           // 128*160 = 20480 entries
    int n = j / 160, k = j % 160;
    cweT[n*160+k] = (k < 128) ? f2b(cw[k*128+n]) : f2b(we[(k-128)*128+n]);
  } else if (i < 57344) {
    int j = i - 53248; int n = j >> 5, k = j & 31; weT[n*32+k] = f2b(we[k*128+n]);
  } else if (i < 57472) {
    int j = i - 57344; cbe[j] = cb[j] + be[j];
  }
}

// ---------- CSR build ----------
__global__ void count_dst(const int* __restrict__ dst, int* __restrict__ counts, int E) {
  for (int i = blockIdx.x * blockDim.x + threadIdx.x; i < E; i += gridDim.x * blockDim.x)
    atomicAdd(&counts[dst[i]], 1);
}
__global__ __launch_bounds__(1024) void scan_offsets(
    const int* __restrict__ counts, int* __restrict__ off,
    int* __restrict__ cursor, int N) {
  __shared__ int part[1024];
  int t = threadIdx.x;
  int chunk = (N + 1023) >> 10;
  int lo = t * chunk, hi = min(lo + chunk, N);
  int s = 0;
  for (int i = lo; i < hi; ++i) s += counts[i];
  part[t] = s;
  __syncthreads();
  for (int d = 1; d < 1024; d <<= 1) {
    int v = (t >= d) ? part[t - d] : 0;
    __syncthreads();
    part[t] += v;
    __syncthreads();
  }
  int run = (t > 0) ? part[t - 1] : 0;
  for (int i = lo; i < hi; ++i) {
    off[i] = run; cursor[i] = run; run += counts[i];
  }
  if (t == 1023) off[N] = part[1023];
}
__global__ void fill_csr(const int* __restrict__ dst, int* __restrict__ cursor,
                         int* __restrict__ eids, int E) {
  for (int i = blockIdx.x * blockDim.x + threadIdx.x; i < E; i += gridDim.x * blockDim.x) {
    int p = atomicAdd(&cursor[dst[i]], 1);
    eids[p] = i;
  }
}

// ---------- inl = bf16(node_feat @ Wn + bn) ----------
__global__ __launch_bounds__(256) void node_linear(
    const float* __restrict__ nf, const ushort* __restrict__ wnT,
    const float* __restrict__ bn, ushort* __restrict__ inl, int N) {
  __shared__ ushort Als[64][136];
  __shared__ ushort Bls[128][136];
  int tid = threadIdx.x;
  int n0 = blockIdx.x * 64;
  { // stage B (Wn^T bf16, 128x128)
    int row = tid >> 1, h = tid & 1;
    const uint4* gp = (const uint4*)(wnT + row*128 + h*64);
    uint4* lp = (uint4*)&Bls[row][h*64];
    #pragma unroll
    for (int i = 0; i < 8; ++i) lp[i] = gp[i];
  }
  { // stage A (node_feat f32 -> bf16)
    int r = tid >> 2, q = tid & 3;
    int n = n0 + r;
    uint4* lp = (uint4*)&Als[r][q*32];
    if (n < N) {
      const float4* fp = (const float4*)(nf + (size_t)n*128 + q*32);
      #pragma unroll
      for (int i = 0; i < 4; ++i) lp[i] = pkf8(fp[2*i], fp[2*i+1]);
    } else {
      uint4 z = {0,0,0,0};
      #pragma unroll
      for (int i = 0; i < 4; ++i) lp[i] = z;
    }
  }
  __syncthreads();
  int l = tid & 63, w = tid >> 6, quad = l >> 4, mr = l & 15;
  f32x4 acc[8];
  #pragma unroll
  for (int nt = 0; nt < 8; ++nt) acc[nt] = (f32x4){0.f,0.f,0.f,0.f};
  #pragma unroll
  for (int kk = 0; kk < 4; ++kk) {
    short8 a = *(const short8*)&Als[w*16 + mr][kk*32 + quad*8];
    #pragma unroll
    for (int nt = 0; nt < 8; ++nt) {
      short8 b = *(const short8*)&Bls[nt*16 + mr][kk*32 + quad*8];
      acc[nt] = __builtin_amdgcn_mfma_f32_16x16x32_bf16(a, b, acc[nt], 0, 0, 0);
    }
  }
  #pragma unroll
  for (int nt = 0; nt < 8; ++nt) {
    int col = nt*16 + mr;
    float bias = bn[col];
    #pragma unroll
    for (int rg = 0; rg < 4; ++rg) {
      int n = n0 + w*16 + quad*4 + rg;
      if (n < N) inl[(size_t)n*128 + col] = f2b(acc[nt][rg] + bias);
    }
  }
}

// ---------- cur = relu(inl[src] + ef @ We + be) ----------
__global__ __launch_bounds__(256) void edge_init(
    const float* __restrict__ ef, const ushort* __restrict__ weT,
    const float* __restrict__ be, const int* __restrict__ esrc,
    const ushort* __restrict__ inl, ushort* __restrict__ cur, int E) {
  __shared__ ushort Als[64][40];
  __shared__ ushort Bls[128][40];
  int tid = threadIdx.x;
  int e0 = blockIdx.x * 64;
  { // stage B (We^T bf16, 128 n x 32 k)
    int row = tid >> 1, h = tid & 1;
    const uint4* gp = (const uint4*)(weT + row*32 + h*16);
    uint4* lp = (uint4*)&Bls[row][h*16];
    lp[0] = gp[0]; lp[1] = gp[1];
  }
  { // stage A (edge_feat f32 64x32 -> bf16)
    int r = tid >> 2, q = tid & 3;
    int e = e0 + r;
    const float4* fp = (const float4*)(ef + (size_t)e*32 + q*8);
    *(uint4*)&Als[r][q*8] = pkf8(fp[0], fp[1]);
  }
  __syncthreads();
  int l = tid & 63, w = tid >> 6, quad = l >> 4, mr = l & 15;
  short8 a = *(const short8*)&Als[w*16 + mr][quad*8];
  f32x4 zero = (f32x4){0.f,0.f,0.f,0.f};
  f32x4 acc[8];
  #pragma unroll
  for (int nt = 0; nt < 8; ++nt) {
    short8 b = *(const short8*)&Bls[nt*16 + mr][quad*8];
    acc[nt] = __builtin_amdgcn_mfma_f32_16x16x32_bf16(a, b, zero, 0, 0, 0);
  }
  int sfour[4];
  #pragma unroll
  for (int rg = 0; rg < 4; ++rg) sfour[rg] = esrc[e0 + w*16 + quad*4 + rg];
  #pragma unroll
  for (int nt = 0; nt < 8; ++nt) {
    int col = nt*16 + mr;
    float bias = be[col];
    #pragma unroll
    for (int rg = 0; rg < 4; ++rg) {
      int e = e0 + w*16 + quad*4 + rg;
      float v = acc[nt][rg] + bias + b2f(inl[(size_t)sfour[rg]*128 + col]);
      cur[(size_t)e*128 + col] = f2b(fmaxf(v, 0.f));
    }
  }
}

// ---------- segment-sum of cur rows into nodes via CSR (4-deep unroll) ----------
__global__ __launch_bounds__(256) void segsum(
    const ushort* __restrict__ cur, const int* __restrict__ off,
    const int* __restrict__ eids, ushort* __restrict__ nagg, int N) {
  int w = threadIdx.x >> 6, l = threadIdx.x & 63;
  int n = blockIdx.x * 4 + w;
  if (n >= N) return;
  int i = off[n], end = off[n + 1];
  float s0 = 0.f, s1 = 0.f;
  for (; i + 4 <= end; i += 4) {
    int ea = eids[i], eb = eids[i + 1], ec = eids[i + 2], ed = eids[i + 3];
    uint va = *(const uint*)(cur + (size_t)ea*128 + 2*l);
    uint vb = *(const uint*)(cur + (size_t)eb*128 + 2*l);
    uint vc = *(const uint*)(cur + (size_t)ec*128 + 2*l);
    uint vd = *(const uint*)(cur + (size_t)ed*128 + 2*l);
    s0 += (lo2f(va) + lo2f(vb)) + (lo2f(vc) + lo2f(vd));
    s1 += (hi2f(va) + hi2f(vb)) + (hi2f(vc) + hi2f(vd));
  }
  for (; i < end; ++i) {
    int ea = eids[i];
    uint va = *(const uint*)(cur + (size_t)ea*128 + 2*l);
    s0 += lo2f(va); s1 += hi2f(va);
  }
  *(uint*)(nagg + (size_t)n*128 + 2*l) = pk2(s0, s1);
}

// ---------- cur = relu([nagg[src]-cur[e^1] | ef] @ [Wc|We]^T + (cb+be) + inl[src]) ----------
// K = 160. B slice per wave held in VGPRs (global/L1-hot); A-tile only in LDS
// -> 21.5 KB LDS, higher occupancy than the 63 KB two-tile version.
__global__ __launch_bounds__(256) void conv_step(
    ushort* __restrict__ cur, const ushort* __restrict__ nagg,
    const ushort* __restrict__ inl, const float* __restrict__ ef,
    const ushort* __restrict__ cweT, const float* __restrict__ cbe,
    const int* __restrict__ esrc, int E) {
  __shared__ ushort Als[64][168];   // 64 x 160 (pad->168)
  int tid = threadIdx.x;
  int e0 = blockIdx.x * 64;
  int l = tid & 63, w = tid >> 6, quad = l >> 4, mr = l & 15;

  // B fragments: wave w covers output cols [32w, 32w+32) = 2 nt tiles, K=160
  short8 bfrag[2][5];
  #pragma unroll
  for (int nt = 0; nt < 2; ++nt) {
    const ushort* bp = cweT + (size_t)(w*32 + nt*16 + mr) * 160;
    #pragma unroll
    for (int kk = 0; kk < 5; ++kk)
      bfrag[nt][kk] = *(const short8*)(bp + kk*32 + quad*8);
  }

  { // stage A: cols[0,128) = nagg[src[e]] - cur[e^1]; cols[128,160) = bf16(ef[e])
    int r = tid >> 2, q = tid & 3;
    int e = e0 + r;
    int s = esrc[e];
    const uint4* cp = (const uint4*)(cur + (size_t)(e ^ 1)*128 + q*32);
    const uint4* np = (const uint4*)(nagg + (size_t)s*128 + q*32);
    uint4* lp = (uint4*)&Als[r][q*32];
    #pragma unroll
    for (int i = 0; i < 4; ++i) lp[i] = sub8(np[i], cp[i]);
    const float4* fp = (const float4*)(ef + (size_t)e*32 + q*8);
    *(uint4*)&Als[r][128 + q*8] = pkf8(fp[0], fp[1]);
  }
  __syncthreads();
  // all reads of cur happened before the barrier; tile-local in-place write below is safe

  #pragma unroll
  for (int m = 0; m < 4; ++m) {
    f32x4 acc0 = (f32x4){0.f,0.f,0.f,0.f};
    f32x4 acc1 = (f32x4){0.f,0.f,0.f,0.f};
    #pragma unroll
    for (int kk = 0; kk < 5; ++kk) {
      short8 a = *(const short8*)&Als[m*16 + mr][kk*32 + quad*8];
      acc0 = __builtin_amdgcn_mfma_f32_16x16x32_bf16(a, bfrag[0][kk], acc0, 0, 0, 0);
      acc1 = __builtin_amdgcn_mfma_f32_16x16x32_bf16(a, bfrag[1][kk], acc1, 0, 0, 0);
    }
    int ebase = e0 + m*16 + quad*4;
    int sfour[4];
    #pragma unroll
    for (int rg = 0; rg < 4; ++rg) sfour[rg] = esrc[ebase + rg];
    int col0 = w*32 + mr, col1 = w*32 + 16 + mr;
    float bias0 = cbe[col0], bias1 = cbe[col1];
    #pragma unroll
    for (int rg = 0; rg < 4; ++rg) {
      float v0 = acc0[rg] + bias0 + b2f(inl[(size_t)sfour[rg]*128 + col0]);
      float v1 = acc1[rg] + bias1 + b2f(inl[(size_t)sfour[rg]*128 + col1]);
      cur[(size_t)(ebase + rg)*128 + col0] = f2b(fmaxf(v0, 0.f));
      cur[(size_t)(ebase + rg)*128 + col1] = f2b(fmaxf(v1, 0.f));
    }
  }
}

// ---------- ract(bf16) = relu(relu(nagg) @ Wo + ob) ----------
__global__ __launch_bounds__(256) void out_linear(
    const ushort* __restrict__ nagg, const ushort* __restrict__ owT,
    const float* __restrict__ ob, ushort* __restrict__ ract, int N) {
  __shared__ ushort Als[64][136];
  __shared__ ushort Bls[128][136];
  int tid = threadIdx.x;
  int n0 = blockIdx.x * 64;
  {
    int row = tid >> 1, h = tid & 1;
    const uint4* gp = (const uint4*)(owT + row*128 + h*64);
    uint4* lp = (uint4*)&Bls[row][h*64];
    #pragma unroll
    for (int i = 0; i < 8; ++i) lp[i] = gp[i];
  }
  {
    int r = tid >> 2, q = tid & 3;
    int n = n0 + r;
    uint4* lp = (uint4*)&Als[r][q*32];
    if (n < N) {
      const uint4* gp = (const uint4*)(nagg + (size_t)n*128 + q*32);
      #pragma unroll
      for (int i = 0; i < 4; ++i) lp[i] = relu8(gp[i]);
    } else {
      uint4 z = {0,0,0,0};
      #pragma unroll
      for (int i = 0; i < 4; ++i) lp[i] = z;
    }
  }
  __syncthreads();
  int l = tid & 63, w = tid >> 6, quad = l >> 4, mr = l & 15;
  f32x4 acc[8];
  #pragma unroll
  for (int nt = 0; nt < 8; ++nt) acc[nt] = (f32x4){0.f,0.f,0.f,0.f};
  #pragma unroll
  for (int kk = 0; kk < 4; ++kk) {
    short8 a = *(const short8*)&Als[w*16 + mr][kk*32 + quad*8];
    #pragma unroll
    for (int nt = 0; nt < 8; ++nt) {
      short8 b = *(const short8*)&Bls[nt*16 + mr][kk*32 + quad*8];
      acc[nt] = __builtin_amdgcn_mfma_f32_16x16x32_bf16(a, b, acc[nt], 0, 0, 0);
    }
  }
  #pragma unroll
  for (int nt = 0; nt < 8; ++nt) {
    int col = nt*16 + mr;
    float bias = ob[col];
    #pragma unroll
    for (int rg = 0; rg < 4; ++rg) {
      int n = n0 + w*16 + quad*4 + rg;
      if (n < N) ract[(size_t)n*128 + col] = f2b(fmaxf(acc[nt][rg] + bias, 0.f));
    }
  }
}

// ---------- per-graph node ranges (graph_ids is sorted), parallel ----------
__global__ void graph_offsets(const int* __restrict__ gids, int* __restrict__ goff,
                              int N, int G) {
  int i = blockIdx.x * blockDim.x + threadIdx.x;
  if (i > N) return;
  int pg = (i == 0) ? -1 : gids[i - 1];
  int cg = (i == N) ? G : gids[i];
  for (int g = pg + 1; g <= cg; ++g) goff[g] = i;
}

// ---------- pool nodes per graph (bf16 in, f32 out) ----------
__global__ __launch_bounds__(256) void graph_pool(
    const ushort* __restrict__ ract, const int* __restrict__ goff,
    float* __restrict__ out, int G) {
  __shared__ float red0[256];
  __shared__ float red1[256];
  int g = blockIdx.x;
  int t = threadIdx.x;
  int c2 = t & 63, rp = t >> 6;      // 2 cols per lane, 4 row-partitions
  int beg = goff[g], end = goff[g + 1];
  float s0 = 0.f, s1 = 0.f;
  for (int n = beg + rp; n < end; n += 4) {
    uint v = *(const uint*)(ract + (size_t)n*128 + 2*c2);
    s0 += lo2f(v); s1 += hi2f(v);
  }
  red0[t] = s0; red1[t] = s1;
  __syncthreads();
  if (rp == 0) {
    float v0 = red0[c2] + red0[c2 + 64] + red0[c2 + 128] + red0[c2 + 192];
    float v1 = red1[c2] + red1[c2 + 64] + red1[c2 + 128] + red1[c2 + 192];
    float2 o; o.x = fmaxf(v0, 0.f); o.y = fmaxf(v1, 0.f);
    *(float2*)(out + (size_t)g*128 + 2*c2) = o;
  }
}

extern "C" void kernel_launch(void* const* d_in, const int* in_sizes, int n_in,
                              void* d_out, int out_size, void* d_ws, size_t ws_size,
                              hipStream_t stream) {
  const float* node_feat = (const float*)d_in[0];
  const float* edge_feat = (const float*)d_in[1];
  const float* wn = (const float*)d_in[2];
  const float* bn = (const float*)d_in[3];
  const float* we = (const float*)d_in[4];
  const float* be = (const float*)d_in[5];
  const float* cw = (const float*)d_in[6];
  const float* cb = (const float*)d_in[7];
  const float* ow = (const float*)d_in[8];
  const float* ob = (const float*)d_in[9];
  const int* esrc = (const int*)d_in[10];
  const int* edst = (const int*)d_in[11];
  const int* gids = (const int*)d_in[12];
  int N = in_sizes[0] / 128;
  int E = in_sizes[10];
  int G = out_size / 128;
  float* out = (float*)d_out;

  char* p = (char*)d_ws;
  auto alloc = [&](size_t bytes) {
    char* r = p;
    p += (bytes + 255) & ~(size_t)255;
    return r;
  };
  // total ws use: ~234 MB (cur 204.8 + inl 12.8 + nagg 12.8 + eids 3.2 + ints ~0.6 + weights ~0.12)
  ushort* cur     = (ushort*)alloc((size_t)E * 128 * 2);
  ushort* inl     = (ushort*)alloc((size_t)N * 128 * 2);   // also reused as ract after last conv
  ushort* nagg    = (ushort*)alloc((size_t)N * 128 * 2);
  int*    eids    = (int*)   alloc((size_t)E * 4);
  int*    counts  = (int*)   alloc((size_t)N * 4);
  int*    off     = (int*)   alloc((size_t)(N + 1) * 4);
  int*    cursor  = (int*)   alloc((size_t)N * 4);
  int*    goff    = (int*)   alloc((size_t)(G + 1) * 4);
  ushort* wnT     = (ushort*)alloc(128 * 128 * 2);
  ushort* weT     = (ushort*)alloc(128 * 32 * 2);
  ushort* cweT    = (ushort*)alloc(128 * 160 * 2);
  ushort* owT     = (ushort*)alloc(128 * 128 * 2);
  float*  cbe     = (float*) alloc(128 * 4);
  ushort* ract    = inl;  // alias: inl dead after last conv_step
  (void)ws_size; (void)n_in;

  zero_ints<<<(N + 255) / 256, 256, 0, stream>>>(counts, N);
  prep_weights<<<225, 256, 0, stream>>>(wn, we, cw, ow, cb, be, wnT, weT, cweT, owT, cbe);
  count_dst<<<1024, 256, 0, stream>>>(edst, counts, E);
  scan_offsets<<<1, 1024, 0, stream>>>(counts, off, cursor, N);
  fill_csr<<<1024, 256, 0, stream>>>(edst, cursor, eids, E);

  node_linear<<<(N + 63) / 64, 256, 0, stream>>>(node_feat, wnT, bn, inl, N);
  edge_init<<<E / 64, 256, 0, stream>>>(edge_feat, weT, be, esrc, inl, cur, E);

  for (int it = 0; it < 3; ++it) {
    segsum<<<(N + 3) / 4, 256, 0, stream>>>(cur, off, eids, nagg, N);
    conv_step<<<E / 64, 256, 0, stream>>>(cur, nagg, inl, edge_feat, cweT, cbe, esrc, E);
  }
  segsum<<<(N + 3) / 4, 256, 0, stream>>>(cur, off, eids, nagg, N);
  out_linear<<<(N + 63) / 64, 256, 0, stream>>>(nagg, owT, ob, ract, N);
  graph_offsets<<<(N + 256) / 256, 256, 0, stream>>>(gids, goff, N, G);
  graph_pool<<<G, 256, 0, stream>>>(ract, goff, out, G);
}

// Round 4
// 1178.944 us; speedup vs baseline: 1.2909x; 1.1312x over previous
//
#include <hip/hip_runtime.h>
#include <hip/hip_bf16.h>
#include <stdint.h>

typedef __attribute__((ext_vector_type(8))) short short8;
typedef __attribute__((ext_vector_type(4))) float f32x4;

__device__ __forceinline__ float b2f(ushort u) {
  union { uint32_t i; float f; } v; v.i = ((uint32_t)u) << 16; return v.f;
}
__device__ __forceinline__ ushort f2b(float f) {
  union { float f; uint32_t i; } v; v.f = f;
  uint32_t x = v.i;
  uint32_t r = x + 0x7FFFu + ((x >> 16) & 1u);
  return (ushort)(r >> 16);
}
__device__ __forceinline__ uint pk2(float lo, float hi) {
  return (uint)f2b(lo) | ((uint)f2b(hi) << 16);
}
__device__ __forceinline__ float lo2f(uint v) { return b2f((ushort)(v & 0xFFFFu)); }
__device__ __forceinline__ float hi2f(uint v) { return b2f((ushort)(v >> 16)); }

__device__ __forceinline__ uint4 pkf8(float4 a, float4 b) {
  uint4 o;
  o.x = pk2(a.x, a.y); o.y = pk2(a.z, a.w);
  o.z = pk2(b.x, b.y); o.w = pk2(b.z, b.w);
  return o;
}
__device__ __forceinline__ uint sub2(uint a, uint b) {
  return pk2(lo2f(a) - lo2f(b), hi2f(a) - hi2f(b));
}
__device__ __forceinline__ uint4 sub8(uint4 a, uint4 b) {
  uint4 o; o.x = sub2(a.x,b.x); o.y = sub2(a.y,b.y); o.z = sub2(a.z,b.z); o.w = sub2(a.w,b.w); return o;
}
// relu(a + b) on packed bf16 pairs, f32 arithmetic
__device__ __forceinline__ uint addrelu2(uint a, uint b) {
  return pk2(fmaxf(lo2f(a) + lo2f(b), 0.f), fmaxf(hi2f(a) + hi2f(b), 0.f));
}
__device__ __forceinline__ uint4 addrelu8(uint4 a, uint4 b) {
  uint4 o; o.x = addrelu2(a.x,b.x); o.y = addrelu2(a.y,b.y);
  o.z = addrelu2(a.z,b.z); o.w = addrelu2(a.w,b.w); return o;
}
__device__ __forceinline__ uint relu2(uint v) {
  uint lo = (v & 0x8000u) ? 0u : (v & 0xFFFFu);
  uint hi = (v & 0x80000000u) ? 0u : (v & 0xFFFF0000u);
  return lo | hi;
}
__device__ __forceinline__ uint4 relu8(uint4 v) {
  uint4 o; o.x = relu2(v.x); o.y = relu2(v.y); o.z = relu2(v.z); o.w = relu2(v.w); return o;
}

__global__ void zero_ints(int* __restrict__ p, int n) {
  int i = blockIdx.x * blockDim.x + threadIdx.x;
  if (i < n) p[i] = 0;
}

// ---------- weight prep: transposes + bf16 + fused conv|edge weight + fused bias ----------
__global__ void prep_weights(const float* __restrict__ wn, const float* __restrict__ we,
                             const float* __restrict__ cw, const float* __restrict__ ow,
                             const float* __restrict__ cb, const float* __restrict__ be,
                             ushort* __restrict__ wnT, ushort* __restrict__ weT,
                             ushort* __restrict__ cweT, ushort* __restrict__ owT,
                             float* __restrict__ cbe) {
  int i = blockIdx.x * blockDim.x + threadIdx.x;
  if (i < 16384) {
    int n = i >> 7, k = i & 127; wnT[n*128+k] = f2b(wn[k*128+n]);
  } else if (i < 32768) {
    int j = i - 16384; int n = j >> 7, k = j & 127; owT[n*128+k] = f2b(ow[k*128+n]);
  } else if (i < 53248) {
    int j = i - 32768;           // 128*160 = 20480 entries
    int n = j / 160, k = j % 160;
    cweT[n*160+k] = (k < 128) ? f2b(cw[k*128+n]) : f2b(we[(k-128)*128+n]);
  } else if (i < 57344) {
    int j = i - 53248; int n = j >> 5, k = j & 31; weT[n*32+k] = f2b(we[k*128+n]);
  } else if (i < 57472) {
    int j = i - 57344; cbe[j] = cb[j] + be[j];
  }
}

// ---------- CSR build ----------
__global__ void count_dst(const int* __restrict__ dst, int* __restrict__ counts, int E) {
  for (int i = blockIdx.x * blockDim.x + threadIdx.x; i < E; i += gridDim.x * blockDim.x)
    atomicAdd(&counts[dst[i]], 1);
}
__global__ __launch_bounds__(1024) void scan_offsets(
    const int* __restrict__ counts, int* __restrict__ off,
    int* __restrict__ cursor, int N) {
  __shared__ int part[1024];
  int t = threadIdx.x;
  int chunk = (N + 1023) >> 10;
  int lo = t * chunk, hi = min(lo + chunk, N);
  int s = 0;
  for (int i = lo; i < hi; ++i) s += counts[i];
  part[t] = s;
  __syncthreads();
  for (int d = 1; d < 1024; d <<= 1) {
    int v = (t >= d) ? part[t - d] : 0;
    __syncthreads();
    part[t] += v;
    __syncthreads();
  }
  int run = (t > 0) ? part[t - 1] : 0;
  for (int i = lo; i < hi; ++i) {
    off[i] = run; cursor[i] = run; run += counts[i];
  }
  if (t == 1023) off[N] = part[1023];
}
__global__ void fill_csr(const int* __restrict__ dst, int* __restrict__ cursor,
                         int* __restrict__ eids, int E) {
  for (int i = blockIdx.x * blockDim.x + threadIdx.x; i < E; i += gridDim.x * blockDim.x) {
    int p = atomicAdd(&cursor[dst[i]], 1);
    eids[p] = i;
  }
}

// ---------- inl = bf16(node_feat @ Wn + bn) ----------
__global__ __launch_bounds__(256) void node_linear(
    const float* __restrict__ nf, const ushort* __restrict__ wnT,
    const float* __restrict__ bn, ushort* __restrict__ inl, int N) {
  __shared__ ushort Als[64][136];
  __shared__ ushort Bls[128][136];
  int tid = threadIdx.x;
  int n0 = blockIdx.x * 64;
  { // stage B (Wn^T bf16, 128x128)
    int row = tid >> 1, h = tid & 1;
    const uint4* gp = (const uint4*)(wnT + row*128 + h*64);
    uint4* lp = (uint4*)&Bls[row][h*64];
    #pragma unroll
    for (int i = 0; i < 8; ++i) lp[i] = gp[i];
  }
  { // stage A (node_feat f32 -> bf16)
    int r = tid >> 2, q = tid & 3;
    int n = n0 + r;
    uint4* lp = (uint4*)&Als[r][q*32];
    if (n < N) {
      const float4* fp = (const float4*)(nf + (size_t)n*128 + q*32);
      #pragma unroll
      for (int i = 0; i < 4; ++i) lp[i] = pkf8(fp[2*i], fp[2*i+1]);
    } else {
      uint4 z = {0,0,0,0};
      #pragma unroll
      for (int i = 0; i < 4; ++i) lp[i] = z;
    }
  }
  __syncthreads();
  int l = tid & 63, w = tid >> 6, quad = l >> 4, mr = l & 15;
  f32x4 acc[8];
  #pragma unroll
  for (int nt = 0; nt < 8; ++nt) acc[nt] = (f32x4){0.f,0.f,0.f,0.f};
  #pragma unroll
  for (int kk = 0; kk < 4; ++kk) {
    short8 a = *(const short8*)&Als[w*16 + mr][kk*32 + quad*8];
    #pragma unroll
    for (int nt = 0; nt < 8; ++nt) {
      short8 b = *(const short8*)&Bls[nt*16 + mr][kk*32 + quad*8];
      acc[nt] = __builtin_amdgcn_mfma_f32_16x16x32_bf16(a, b, acc[nt], 0, 0, 0);
    }
  }
  #pragma unroll
  for (int nt = 0; nt < 8; ++nt) {
    int col = nt*16 + mr;
    float bias = bn[col];
    #pragma unroll
    for (int rg = 0; rg < 4; ++rg) {
      int n = n0 + w*16 + quad*4 + rg;
      if (n < N) inl[(size_t)n*128 + col] = f2b(acc[nt][rg] + bias);
    }
  }
}

// ---------- cur = relu(inl[src] + ef @ We + be) ----------
// 3-phase: MFMA -> LDS C (bf16, +bias), then packed epilogue (16B inl gather + 16B stores)
__global__ __launch_bounds__(256) void edge_init(
    const float* __restrict__ ef, const ushort* __restrict__ weT,
    const float* __restrict__ be, const int* __restrict__ esrc,
    const ushort* __restrict__ inl, ushort* __restrict__ cur, int E) {
  __shared__ ushort Als[64][40];    // 64 x 32 (pad 40)
  __shared__ ushort Cls[64][136];   // 64 x 128 (pad 136 = 17x16B)
  int tid = threadIdx.x;
  int e0 = blockIdx.x * 64;
  int l = tid & 63, w = tid >> 6, quad = l >> 4, mr = l & 15;
  int r = tid >> 2, q = tid & 3;

  // B fragments in VGPRs: wave w covers cols [32w, 32w+32) = 2 nt tiles, K=32
  short8 bfrag[2];
  #pragma unroll
  for (int nt = 0; nt < 2; ++nt)
    bfrag[nt] = *(const short8*)(weT + (size_t)(w*32 + nt*16 + mr)*32 + quad*8);

  { // stage A (edge_feat f32 64x32 -> bf16)
    const float4* fp = (const float4*)(ef + (size_t)(e0 + r)*32 + q*8);
    *(uint4*)&Als[r][q*8] = pkf8(fp[0], fp[1]);
  }
  __syncthreads();

  int col0 = w*32 + mr, col1 = w*32 + 16 + mr;
  float bias0 = be[col0], bias1 = be[col1];
  #pragma unroll
  for (int m = 0; m < 4; ++m) {
    short8 a = *(const short8*)&Als[m*16 + mr][quad*8];
    f32x4 zero = (f32x4){0.f,0.f,0.f,0.f};
    f32x4 acc0 = __builtin_amdgcn_mfma_f32_16x16x32_bf16(a, bfrag[0], zero, 0, 0, 0);
    f32x4 acc1 = __builtin_amdgcn_mfma_f32_16x16x32_bf16(a, bfrag[1], zero, 0, 0, 0);
    #pragma unroll
    for (int rg = 0; rg < 4; ++rg) {
      int row = m*16 + quad*4 + rg;
      Cls[row][col0] = f2b(acc0[rg] + bias0);
      Cls[row][col1] = f2b(acc1[rg] + bias1);
    }
  }
  __syncthreads();

  { // packed epilogue: cur[e] = relu(C + inl[src[e]])
    int e = e0 + r;
    int s = esrc[e];
    const uint4* cl = (const uint4*)&Cls[r][q*32];
    const uint4* ip = (const uint4*)(inl + (size_t)s*128 + q*32);
    uint4* op = (uint4*)(cur + (size_t)e*128 + q*32);
    #pragma unroll
    for (int i = 0; i < 4; ++i) op[i] = addrelu8(cl[i], ip[i]);
  }
}

// ---------- segment-sum of cur rows into nodes via CSR (8-deep unroll) ----------
__global__ __launch_bounds__(256) void segsum(
    const ushort* __restrict__ cur, const int* __restrict__ off,
    const int* __restrict__ eids, ushort* __restrict__ nagg, int N) {
  int w = threadIdx.x >> 6, l = threadIdx.x & 63;
  int n = blockIdx.x * 4 + w;
  if (n >= N) return;
  int i = off[n], end = off[n + 1];
  float s0 = 0.f, s1 = 0.f;
  for (; i + 8 <= end; i += 8) {
    int e[8]; uint v[8];
    #pragma unroll
    for (int j = 0; j < 8; ++j) e[j] = eids[i + j];
    #pragma unroll
    for (int j = 0; j < 8; ++j) v[j] = *(const uint*)(cur + (size_t)e[j]*128 + 2*l);
    #pragma unroll
    for (int j = 0; j < 8; ++j) { s0 += lo2f(v[j]); s1 += hi2f(v[j]); }
  }
  for (; i < end; ++i) {
    int ea = eids[i];
    uint va = *(const uint*)(cur + (size_t)ea*128 + 2*l);
    s0 += lo2f(va); s1 += hi2f(va);
  }
  *(uint*)(nagg + (size_t)n*128 + 2*l) = pk2(s0, s1);
}

// ---------- cur = relu([nagg[src]-cur[e^1] | ef] @ [Wc|We]^T + (cb+be) + inl[src]) ----------
// K = 160. B slice per wave in VGPRs; A-tile in LDS; C round-trips LDS so the
// epilogue does 16B inl gathers + 16B packed stores instead of 2B scalars.
__global__ __launch_bounds__(256) void conv_step(
    ushort* __restrict__ cur, const ushort* __restrict__ nagg,
    const ushort* __restrict__ inl, const float* __restrict__ ef,
    const ushort* __restrict__ cweT, const float* __restrict__ cbe,
    const int* __restrict__ esrc, int E) {
  __shared__ ushort Als[64][168];   // 64 x 160 (pad->168 = 21x16B)
  __shared__ ushort Cls[64][136];   // 64 x 128 (pad->136 = 17x16B)
  int tid = threadIdx.x;
  int e0 = blockIdx.x * 64;
  int l = tid & 63, w = tid >> 6, quad = l >> 4, mr = l & 15;
  int r = tid >> 2, q = tid & 3;

  // B fragments: wave w covers output cols [32w, 32w+32) = 2 nt tiles, K=160
  short8 bfrag[2][5];
  #pragma unroll
  for (int nt = 0; nt < 2; ++nt) {
    const ushort* bp = cweT + (size_t)(w*32 + nt*16 + mr) * 160;
    #pragma unroll
    for (int kk = 0; kk < 5; ++kk)
      bfrag[nt][kk] = *(const short8*)(bp + kk*32 + quad*8);
  }

  { // stage A: cols[0,128) = nagg[src[e]] - cur[e^1]; cols[128,160) = bf16(ef[e])
    int e = e0 + r;
    int s = esrc[e];
    const uint4* cp = (const uint4*)(cur + (size_t)(e ^ 1)*128 + q*32);
    const uint4* np = (const uint4*)(nagg + (size_t)s*128 + q*32);
    uint4* lp = (uint4*)&Als[r][q*32];
    #pragma unroll
    for (int i = 0; i < 4; ++i) lp[i] = sub8(np[i], cp[i]);
    const float4* fp = (const float4*)(ef + (size_t)e*32 + q*8);
    *(uint4*)&Als[r][128 + q*8] = pkf8(fp[0], fp[1]);
  }
  __syncthreads();

  int col0 = w*32 + mr, col1 = w*32 + 16 + mr;
  float bias0 = cbe[col0], bias1 = cbe[col1];
  #pragma unroll
  for (int m = 0; m < 4; ++m) {
    f32x4 acc0 = (f32x4){0.f,0.f,0.f,0.f};
    f32x4 acc1 = (f32x4){0.f,0.f,0.f,0.f};
    #pragma unroll
    for (int kk = 0; kk < 5; ++kk) {
      short8 a = *(const short8*)&Als[m*16 + mr][kk*32 + quad*8];
      acc0 = __builtin_amdgcn_mfma_f32_16x16x32_bf16(a, bfrag[0][kk], acc0, 0, 0, 0);
      acc1 = __builtin_amdgcn_mfma_f32_16x16x32_bf16(a, bfrag[1][kk], acc1, 0, 0, 0);
    }
    #pragma unroll
    for (int rg = 0; rg < 4; ++rg) {
      int row = m*16 + quad*4 + rg;
      Cls[row][col0] = f2b(acc0[rg] + bias0);
      Cls[row][col1] = f2b(acc1[rg] + bias1);
    }
  }
  __syncthreads();

  { // packed epilogue: cur[e] = relu(C + inl[src[e]])  (cur reads all done pre-barrier)
    int e = e0 + r;
    int s = esrc[e];
    const uint4* cl = (const uint4*)&Cls[r][q*32];
    const uint4* ip = (const uint4*)(inl + (size_t)s*128 + q*32);
    uint4* op = (uint4*)(cur + (size_t)e*128 + q*32);
    #pragma unroll
    for (int i = 0; i < 4; ++i) op[i] = addrelu8(cl[i], ip[i]);
  }
}

// ---------- ract(bf16) = relu(relu(nagg) @ Wo + ob) ----------
__global__ __launch_bounds__(256) void out_linear(
    const ushort* __restrict__ nagg, const ushort* __restrict__ owT,
    const float* __restrict__ ob, ushort* __restrict__ ract, int N) {
  __shared__ ushort Als[64][136];
  __shared__ ushort Bls[128][136];
  int tid = threadIdx.x;
  int n0 = blockIdx.x * 64;
  {
    int row = tid >> 1, h = tid & 1;
    const uint4* gp = (const uint4*)(owT + row*128 + h*64);
    uint4* lp = (uint4*)&Bls[row][h*64];
    #pragma unroll
    for (int i = 0; i < 8; ++i) lp[i] = gp[i];
  }
  {
    int r = tid >> 2, q = tid & 3;
    int n = n0 + r;
    uint4* lp = (uint4*)&Als[r][q*32];
    if (n < N) {
      const uint4* gp = (const uint4*)(nagg + (size_t)n*128 + q*32);
      #pragma unroll
      for (int i = 0; i < 4; ++i) lp[i] = relu8(gp[i]);
    } else {
      uint4 z = {0,0,0,0};
      #pragma unroll
      for (int i = 0; i < 4; ++i) lp[i] = z;
    }
  }
  __syncthreads();
  int l = tid & 63, w = tid >> 6, quad = l >> 4, mr = l & 15;
  f32x4 acc[8];
  #pragma unroll
  for (int nt = 0; nt < 8; ++nt) acc[nt] = (f32x4){0.f,0.f,0.f,0.f};
  #pragma unroll
  for (int kk = 0; kk < 4; ++kk) {
    short8 a = *(const short8*)&Als[w*16 + mr][kk*32 + quad*8];
    #pragma unroll
    for (int nt = 0; nt < 8; ++nt) {
      short8 b = *(const short8*)&Bls[nt*16 + mr][kk*32 + quad*8];
      acc[nt] = __builtin_amdgcn_mfma_f32_16x16x32_bf16(a, b, acc[nt], 0, 0, 0);
    }
  }
  #pragma unroll
  for (int nt = 0; nt < 8; ++nt) {
    int col = nt*16 + mr;
    float bias = ob[col];
    #pragma unroll
    for (int rg = 0; rg < 4; ++rg) {
      int n = n0 + w*16 + quad*4 + rg;
      if (n < N) ract[(size_t)n*128 + col] = f2b(fmaxf(acc[nt][rg] + bias, 0.f));
    }
  }
}

// ---------- per-graph node ranges (graph_ids is sorted), parallel ----------
__global__ void graph_offsets(const int* __restrict__ gids, int* __restrict__ goff,
                              int N, int G) {
  int i = blockIdx.x * blockDim.x + threadIdx.x;
  if (i > N) return;
  int pg = (i == 0) ? -1 : gids[i - 1];
  int cg = (i == N) ? G : gids[i];
  for (int g = pg + 1; g <= cg; ++g) goff[g] = i;
}

// ---------- pool nodes per graph (bf16 in, f32 out) ----------
__global__ __launch_bounds__(256) void graph_pool(
    const ushort* __restrict__ ract, const int* __restrict__ goff,
    float* __restrict__ out, int G) {
  __shared__ float red0[256];
  __shared__ float red1[256];
  int g = blockIdx.x;
  int t = threadIdx.x;
  int c2 = t & 63, rp = t >> 6;      // 2 cols per lane, 4 row-partitions
  int beg = goff[g], end = goff[g + 1];
  float s0 = 0.f, s1 = 0.f;
  for (int n = beg + rp; n < end; n += 4) {
    uint v = *(const uint*)(ract + (size_t)n*128 + 2*c2);
    s0 += lo2f(v); s1 += hi2f(v);
  }
  red0[t] = s0; red1[t] = s1;
  __syncthreads();
  if (rp == 0) {
    float v0 = red0[c2] + red0[c2 + 64] + red0[c2 + 128] + red0[c2 + 192];
    float v1 = red1[c2] + red1[c2 + 64] + red1[c2 + 128] + red1[c2 + 192];
    float2 o; o.x = fmaxf(v0, 0.f); o.y = fmaxf(v1, 0.f);
    *(float2*)(out + (size_t)g*128 + 2*c2) = o;
  }
}

extern "C" void kernel_launch(void* const* d_in, const int* in_sizes, int n_in,
                              void* d_out, int out_size, void* d_ws, size_t ws_size,
                              hipStream_t stream) {
  const float* node_feat = (const float*)d_in[0];
  const float* edge_feat = (const float*)d_in[1];
  const float* wn = (const float*)d_in[2];
  const float* bn = (const float*)d_in[3];
  const float* we = (const float*)d_in[4];
  const float* be = (const float*)d_in[5];
  const float* cw = (const float*)d_in[6];
  const float* cb = (const float*)d_in[7];
  const float* ow = (const float*)d_in[8];
  const float* ob = (const float*)d_in[9];
  const int* esrc = (const int*)d_in[10];
  const int* edst = (const int*)d_in[11];
  const int* gids = (const int*)d_in[12];
  int N = in_sizes[0] / 128;
  int E = in_sizes[10];
  int G = out_size / 128;
  float* out = (float*)d_out;

  char* p = (char*)d_ws;
  auto alloc = [&](size_t bytes) {
    char* r = p;
    p += (bytes + 255) & ~(size_t)255;
    return r;
  };
  // total ws use: ~234 MB (cur 204.8 + inl 12.8 + nagg 12.8 + eids 3.2 + ints ~0.6 + weights ~0.12)
  ushort* cur     = (ushort*)alloc((size_t)E * 128 * 2);
  ushort* inl     = (ushort*)alloc((size_t)N * 128 * 2);   // also reused as ract after last conv
  ushort* nagg    = (ushort*)alloc((size_t)N * 128 * 2);
  int*    eids    = (int*)   alloc((size_t)E * 4);
  int*    counts  = (int*)   alloc((size_t)N * 4);
  int*    off     = (int*)   alloc((size_t)(N + 1) * 4);
  int*    cursor  = (int*)   alloc((size_t)N * 4);
  int*    goff    = (int*)   alloc((size_t)(G + 1) * 4);
  ushort* wnT     = (ushort*)alloc(128 * 128 * 2);
  ushort* weT     = (ushort*)alloc(128 * 32 * 2);
  ushort* cweT    = (ushort*)alloc(128 * 160 * 2);
  ushort* owT     = (ushort*)alloc(128 * 128 * 2);
  float*  cbe     = (float*) alloc(128 * 4);
  ushort* ract    = inl;  // alias: inl dead after last conv_step
  (void)ws_size; (void)n_in;

  zero_ints<<<(N + 255) / 256, 256, 0, stream>>>(counts, N);
  prep_weights<<<225, 256, 0, stream>>>(wn, we, cw, ow, cb, be, wnT, weT, cweT, owT, cbe);
  count_dst<<<1024, 256, 0, stream>>>(edst, counts, E);
  scan_offsets<<<1, 1024, 0, stream>>>(counts, off, cursor, N);
  fill_csr<<<1024, 256, 0, stream>>>(edst, cursor, eids, E);

  node_linear<<<(N + 63) / 64, 256, 0, stream>>>(node_feat, wnT, bn, inl, N);
  edge_init<<<E / 64, 256, 0, stream>>>(edge_feat, weT, be, esrc, inl, cur, E);

  for (int it = 0; it < 3; ++it) {
    segsum<<<(N + 3) / 4, 256, 0, stream>>>(cur, off, eids, nagg, N);
    conv_step<<<E / 64, 256, 0, stream>>>(cur, nagg, inl, edge_feat, cweT, cbe, esrc, E);
  }
  segsum<<<(N + 3) / 4, 256, 0, stream>>>(cur, off, eids, nagg, N);
  out_linear<<<(N + 63) / 64, 256, 0, stream>>>(nagg, owT, ob, ract, N);
  graph_offsets<<<(N + 256) / 256, 256, 0, stream>>>(gids, goff, N, G);
  graph_pool<<<G, 256, 0, stream>>>(ract, goff, out, G);
}